// Round 1
// baseline (353.742 us; speedup 1.0000x reference)
//
#include <hip/hip_runtime.h>
#include <hip/hip_bf16.h>
#include <math.h>

#define D_MODEL 1024
#define HS 2048
#define HE 1024
#define NEXP 8
#define NTOK 4096
#define NSLOT 8192

typedef __attribute__((ext_vector_type(4))) float f32x4;
typedef __attribute__((ext_vector_type(8))) short bf16x8;

__device__ __forceinline__ short f2b(float f) {
  __hip_bfloat16 h = __float2bfloat16(f);
  return *reinterpret_cast<short*>(&h);
}

__device__ __forceinline__ void gl_lds16(const void* g, void* l) {
  __builtin_amdgcn_global_load_lds(
      (const __attribute__((address_space(1))) void*)g,
      (__attribute__((address_space(3))) void*)l, 16, 0, 0);
}

// ---------------- elementwise converts ----------------
__global__ __launch_bounds__(256) void cvt_x_kernel(const float* __restrict__ in,
                                                    short* __restrict__ out) {
  int i = blockIdx.x * 256 + threadIdx.x;  // over NTOK*D/4
  const float4 v = ((const float4*)in)[i];
  short4 o;
  o.x = f2b(v.x); o.y = f2b(v.y); o.z = f2b(v.z); o.w = f2b(v.w);
  ((short4*)out)[i] = o;
}

// in [R][C] f32 -> out [C][R] bf16, batched over blockIdx.z
__global__ __launch_bounds__(256) void transpose_cvt(const float* __restrict__ in,
                                                     short* __restrict__ out,
                                                     int R, int C) {
  __shared__ float tile[32][33];
  const int tx = threadIdx.x;  // 0..31
  const int ty = threadIdx.y;  // 0..7
  const int c0 = blockIdx.x * 32;
  const int r0 = blockIdx.y * 32;
  const size_t bo = (size_t)blockIdx.z * R * C;
#pragma unroll
  for (int i = 0; i < 4; i++)
    tile[ty + i * 8][tx] = in[bo + (size_t)(r0 + ty + i * 8) * C + c0 + tx];
  __syncthreads();
#pragma unroll
  for (int i = 0; i < 4; i++)
    out[bo + (size_t)(c0 + ty + i * 8) * R + r0 + tx] = f2b(tile[tx][ty + i * 8]);
}

// ---------------- router ----------------
__global__ __launch_bounds__(64) void router_kernel(
    const float* __restrict__ x, const float* __restrict__ temb,
    const float* __restrict__ rw, const float* __restrict__ rbias,
    int* __restrict__ topk, float* __restrict__ gates) {
  const int t = blockIdx.x;
  const int lane = threadIdx.x;
  const float* xr = x + (size_t)t * D_MODEL;
  const float* tr = temb + (size_t)(t >> 10) * D_MODEL;  // T=1024
  float acc[NEXP];
#pragma unroll
  for (int e = 0; e < NEXP; e++) acc[e] = 0.f;
  for (int j = lane; j < D_MODEL; j += 64) {
    float xv = xr[j];
    const float* w = rw + (size_t)j * NEXP;
#pragma unroll
    for (int e = 0; e < NEXP; e++) acc[e] += xv * w[e];
  }
  for (int j = lane; j < D_MODEL; j += 64) {
    float tv = tr[j];
    const float* w = rw + (size_t)(D_MODEL + j) * NEXP;
#pragma unroll
    for (int e = 0; e < NEXP; e++) acc[e] += tv * w[e];
  }
#pragma unroll
  for (int off = 32; off > 0; off >>= 1)
#pragma unroll
    for (int e = 0; e < NEXP; e++) acc[e] += __shfl_down(acc[e], off);
  if (lane == 0) {
    float s[NEXP], sel[NEXP];
#pragma unroll
    for (int e = 0; e < NEXP; e++) {
      s[e] = 1.f / (1.f + expf(-acc[e]));
      sel[e] = s[e] + rbias[e];
    }
    int i0 = 0;
#pragma unroll
    for (int e = 1; e < NEXP; e++) if (sel[e] > sel[i0]) i0 = e;
    int i1 = (i0 == 0) ? 1 : 0;
#pragma unroll
    for (int e = 0; e < NEXP; e++) if (e != i0 && sel[e] > sel[i1]) i1 = e;
    float s0 = s[i0], s1 = s[i1], den = s0 + s1;
    float g0, g1;
    if (den > 1e-9f) { g0 = s0 / (den + 1e-9f); g1 = s1 / (den + 1e-9f); }
    else { g0 = 0.5f; g1 = 0.5f; }
    topk[t * 2] = i0; topk[t * 2 + 1] = i1;
    gates[t * 2] = g0; gates[t * 2 + 1] = g1;
  }
}

// ---------------- grouping ----------------
__global__ void init_cnt(int* cnt) { if (threadIdx.x < NEXP) cnt[threadIdx.x] = 0; }

__global__ __launch_bounds__(256) void hist_kernel(const int* __restrict__ topk,
                                                   int* __restrict__ cnt) {
  int i = blockIdx.x * 256 + threadIdx.x;
  if (i < NSLOT) atomicAdd(&cnt[topk[i]], 1);
}

__global__ void scan_kernel(const int* __restrict__ cnt, int* __restrict__ offs,
                            int* __restrict__ cursor) {
  if (threadIdx.x == 0) {
    int a = 0;
    for (int e = 0; e < NEXP; e++) { offs[e] = a; cursor[e] = a; a += cnt[e]; }
    offs[NEXP] = a;
  }
}

__global__ __launch_bounds__(256) void fill_kernel(const int* __restrict__ topk,
                                                   int* __restrict__ cursor,
                                                   int* __restrict__ perm) {
  int i = blockIdx.x * 256 + threadIdx.x;
  if (i < NSLOT) {
    int pos = atomicAdd(&cursor[topk[i]], 1);
    perm[pos] = i;
  }
}

// ---------------- GEMM (B pre-transposed: B[N][K] bf16) ----------------
// MODE 0: plain, C f32 [M][N]
// MODE 1: grouped (z=expert), gather A rows via perm>>1, epilogue exact-GELU -> bf16 C rows at global slot index
// MODE 2: grouped, A rows dense in perm order, scatter C rows via perm -> f32 C
template <int MODE>
__global__ __launch_bounds__(256, 2) void gemm_bt(
    const short* __restrict__ A, const short* __restrict__ B, void* __restrict__ C,
    int M, int N, int K, const int* __restrict__ perm, const int* __restrict__ offs) {
  __shared__ __align__(16) short As[4096];  // [128][32]
  __shared__ __align__(16) short Bs[4096];  // [128][32]

  const int t = threadIdx.x;
  const int tile_n = blockIdx.x * 128;
  const int m0 = blockIdx.y * 128;

  int rbeg = 0, rend = M;
  const short* Bp = B;
  if (MODE >= 1) {
    const int e = blockIdx.z;
    rbeg = offs[e];
    rend = offs[e + 1];
    if (m0 >= rend - rbeg) return;
    Bp = B + (size_t)e * (size_t)HE * D_MODEL;
  }

  const int r = t >> 2;
  const int c8 = (t & 3) * 8;

  size_t arow0, arow1;
  if (MODE == 0) {
    arow0 = (size_t)(m0 + r) * K;
    arow1 = (size_t)(m0 + 64 + r) * K;
  } else if (MODE == 1) {
    int gi0 = min(rbeg + m0 + r, rend - 1);
    int gi1 = min(rbeg + m0 + 64 + r, rend - 1);
    arow0 = (size_t)(perm[gi0] >> 1) * K;
    arow1 = (size_t)(perm[gi1] >> 1) * K;
  } else {
    int gi0 = min(rbeg + m0 + r, rend - 1);
    int gi1 = min(rbeg + m0 + 64 + r, rend - 1);
    arow0 = (size_t)gi0 * K;
    arow1 = (size_t)gi1 * K;
  }
  const short* Ap0 = A + arow0 + c8;
  const short* Ap1 = A + arow1 + c8;
  const short* Bp0 = Bp + (size_t)(tile_n + r) * K + c8;
  const short* Bp1 = Bp + (size_t)(tile_n + 64 + r) * K + c8;

  const int lane = t & 63;
  const int wv = t >> 6;
  const int wm = (wv >> 1) * 64;
  const int wn = (wv & 1) * 64;
  const int lr = lane & 15;
  const int lk = (lane >> 4) * 8;

  f32x4 acc[4][4] = {};

  for (int k0 = 0; k0 < K; k0 += 32) {
    gl_lds16(Ap0 + k0, &As[t * 8]);
    gl_lds16(Ap1 + k0, &As[2048 + t * 8]);
    gl_lds16(Bp0 + k0, &Bs[t * 8]);
    gl_lds16(Bp1 + k0, &Bs[2048 + t * 8]);
    __syncthreads();
    bf16x8 af[4], bfr[4];
#pragma unroll
    for (int m = 0; m < 4; m++)
      af[m] = *(const bf16x8*)&As[(wm + m * 16 + lr) * 32 + lk];
#pragma unroll
    for (int n = 0; n < 4; n++)
      bfr[n] = *(const bf16x8*)&Bs[(wn + n * 16 + lr) * 32 + lk];
#pragma unroll
    for (int m = 0; m < 4; m++)
#pragma unroll
      for (int n = 0; n < 4; n++)
        acc[m][n] = __builtin_amdgcn_mfma_f32_16x16x32_bf16(af[m], bfr[n], acc[m][n], 0, 0, 0);
    __syncthreads();
  }

  const int rq = (lane >> 4) * 4;
#pragma unroll
  for (int m = 0; m < 4; m++) {
#pragma unroll
    for (int j = 0; j < 4; j++) {
      const int rl = wm + m * 16 + rq + j;  // row within tile
      if (MODE == 0) {
        float* Cp = (float*)C + (size_t)(m0 + rl) * N + tile_n + wn + lr;
#pragma unroll
        for (int n = 0; n < 4; n++) Cp[n * 16] = acc[m][n][j];
      } else {
        const int gi = rbeg + m0 + rl;
        if (gi < rend) {
          if (MODE == 1) {
            short* Cp = (short*)C + (size_t)gi * HE + tile_n + wn + lr;
#pragma unroll
            for (int n = 0; n < 4; n++) {
              float v = acc[m][n][j];
              Cp[n * 16] = f2b(0.5f * v * (1.0f + erff(v * 0.70710678118654752f)));
            }
          } else {
            const int slot = perm[gi];
            float* Cp = (float*)C + (size_t)slot * D_MODEL + tile_n + wn + lr;
#pragma unroll
            for (int n = 0; n < 4; n++) Cp[n * 16] = acc[m][n][j];
          }
        }
      }
    }
  }
}

// ---------------- activations / combine ----------------
__global__ __launch_bounds__(256) void silu_mul_kernel(const float* __restrict__ H,
                                                       short* __restrict__ u) {
  int i = blockIdx.x * 256 + threadIdx.x;  // over NTOK*HS/4
  int base = i * 4;
  int row = base >> 11;      // / HS
  int col = base & (HS - 1);
  const float4 a = *(const float4*)&H[(size_t)row * 4096 + col];
  const float4 b = *(const float4*)&H[(size_t)row * 4096 + HS + col];
  short4 o;
  o.x = f2b(a.x / (1.f + expf(-a.x)) * b.x);
  o.y = f2b(a.y / (1.f + expf(-a.y)) * b.y);
  o.z = f2b(a.z / (1.f + expf(-a.z)) * b.z);
  o.w = f2b(a.w / (1.f + expf(-a.w)) * b.w);
  ((short4*)u)[i] = o;
}

__global__ __launch_bounds__(256) void combine_kernel(
    const float* __restrict__ sh, const float* __restrict__ yslot,
    const float* __restrict__ gates, float* __restrict__ out) {
  int i = blockIdx.x * 256 + threadIdx.x;  // over NTOK*D/4
  int base = i * 4;
  int tk = base >> 10;
  float g0 = gates[tk * 2], g1 = gates[tk * 2 + 1];
  int col = base & (D_MODEL - 1);
  const float4 s = *(const float4*)&sh[base];
  const float4 y0 = *(const float4*)&yslot[(size_t)(tk * 2) * D_MODEL + col];
  const float4 y1 = *(const float4*)&yslot[(size_t)(tk * 2 + 1) * D_MODEL + col];
  const float inv3 = 1.0f / 3.0f;
  float4 o;
  o.x = (s.x + g0 * y0.x + g1 * y1.x) * inv3;
  o.y = (s.y + g0 * y0.y + g1 * y1.y) * inv3;
  o.z = (s.z + g0 * y0.z + g1 * y1.z) * inv3;
  o.w = (s.w + g0 * y0.w + g1 * y1.w) * inv3;
  *(float4*)&out[base] = o;
}

// ---------------- launch ----------------
extern "C" void kernel_launch(void* const* d_in, const int* in_sizes, int n_in,
                              void* d_out, int out_size, void* d_ws, size_t ws_size,
                              hipStream_t stream) {
  const float* x = (const float*)d_in[0];
  const float* temb = (const float*)d_in[1];
  const float* rw = (const float*)d_in[2];
  const float* rbias = (const float*)d_in[3];
  const float* w1 = (const float*)d_in[4];
  const float* w3 = (const float*)d_in[5];
  const float* w2 = (const float*)d_in[6];
  const float* W1e = (const float*)d_in[7];
  const float* W2e = (const float*)d_in[8];
  float* out = (float*)d_out;

  const size_t MB = 1ull << 20;
  char* w = (char*)d_ws;
  short* xb   = (short*)(w + 0 * MB);    // 8 MB  [4096][1024] bf16
  short* w13T = (short*)(w + 8 * MB);    // 8 MB  [4096][1024] bf16 (w1T rows 0..2047, w3T rows 2048..4095)
  short* w2T  = (short*)(w + 16 * MB);   // 4 MB  [1024][2048]
  short* W1eT = (short*)(w + 20 * MB);   // 16 MB [8][1024][1024]
  short* W2eT = (short*)(w + 36 * MB);   // 16 MB [8][1024][1024]
  float* H    = (float*)(w + 52 * MB);   // 64 MB [4096][4096]
  short* ubuf = (short*)(w + 116 * MB);  // 16 MB [4096][2048] bf16
  float* shbuf= (float*)(w + 132 * MB);  // 16 MB [4096][1024]
  short* hexpb= (short*)(w + 148 * MB);  // 16 MB [8192][1024] bf16
  float* yslot= (float*)(w + 164 * MB);  // 32 MB [8192][1024]
  float* gates= (float*)(w + 196 * MB);  // 32 KB
  int* topk   = (int*)(w + 196 * MB + 32 * 1024);
  int* perm   = (int*)(w + 196 * MB + 64 * 1024);
  int* cnt    = (int*)(w + 196 * MB + 96 * 1024);
  int* offs   = cnt + 16;
  int* cursor = cnt + 32;

  // converts / transposes
  cvt_x_kernel<<<NTOK * D_MODEL / 4 / 256, 256, 0, stream>>>(x, xb);
  transpose_cvt<<<dim3(HS / 32, D_MODEL / 32, 1), dim3(32, 8), 0, stream>>>(w1, w13T, D_MODEL, HS);
  transpose_cvt<<<dim3(HS / 32, D_MODEL / 32, 1), dim3(32, 8), 0, stream>>>(w3, w13T + (size_t)HS * D_MODEL, D_MODEL, HS);
  transpose_cvt<<<dim3(D_MODEL / 32, HS / 32, 1), dim3(32, 8), 0, stream>>>(w2, w2T, HS, D_MODEL);
  transpose_cvt<<<dim3(HE / 32, D_MODEL / 32, NEXP), dim3(32, 8), 0, stream>>>(W1e, W1eT, D_MODEL, HE);
  transpose_cvt<<<dim3(D_MODEL / 32, HE / 32, NEXP), dim3(32, 8), 0, stream>>>(W2e, W2eT, HE, D_MODEL);

  // router + grouping
  router_kernel<<<NTOK, 64, 0, stream>>>(x, temb, rw, rbias, topk, gates);
  init_cnt<<<1, 64, 0, stream>>>(cnt);
  hist_kernel<<<NSLOT / 256, 256, 0, stream>>>(topk, cnt);
  scan_kernel<<<1, 64, 0, stream>>>(cnt, offs, cursor);
  fill_kernel<<<NSLOT / 256, 256, 0, stream>>>(topk, cursor, perm);

  // shared expert
  gemm_bt<0><<<dim3(32, 32, 1), 256, 0, stream>>>(xb, w13T, H, NTOK, 4096, D_MODEL, nullptr, nullptr);
  silu_mul_kernel<<<NTOK * HS / 4 / 256, 256, 0, stream>>>(H, ubuf);
  gemm_bt<0><<<dim3(8, 32, 1), 256, 0, stream>>>(ubuf, w2T, shbuf, NTOK, D_MODEL, HS, nullptr, nullptr);

  // routed experts (grouped)
  gemm_bt<1><<<dim3(8, 64, 8), 256, 0, stream>>>(xb, W1eT, hexpb, NSLOT, HE, D_MODEL, perm, offs);
  gemm_bt<2><<<dim3(8, 64, 8), 256, 0, stream>>>(hexpb, W2eT, yslot, NSLOT, D_MODEL, HE, perm, offs);

  // combine
  combine_kernel<<<NTOK * D_MODEL / 4 / 256, 256, 0, stream>>>(shbuf, yslot, gates, out);
}

// Round 2
// 265.361 us; speedup vs baseline: 1.3331x; 1.3331x over previous
//
#include <hip/hip_runtime.h>
#include <hip/hip_bf16.h>
#include <math.h>

#define D_MODEL 1024
#define HS 2048
#define HE 1024
#define NEXP 8
#define NTOK 4096
#define NSLOT 8192

typedef __attribute__((ext_vector_type(4))) float f32x4;
typedef __attribute__((ext_vector_type(8))) short bf16x8;

__device__ __forceinline__ short f2b(float f) {
  __hip_bfloat16 h = __float2bfloat16(f);
  return *reinterpret_cast<short*>(&h);
}
__device__ __forceinline__ float b2f(short s) {
  return __bfloat162float(*reinterpret_cast<__hip_bfloat16*>(&s));
}

__device__ __forceinline__ void gl_lds16(const void* g, void* l) {
  __builtin_amdgcn_global_load_lds(
      (const __attribute__((address_space(1))) void*)g,
      (__attribute__((address_space(3))) void*)l, 16, 0, 0);
}

// ---------------- converts ----------------
__global__ __launch_bounds__(256) void cvt_x_kernel(const float* __restrict__ in,
                                                    short* __restrict__ out) {
  int i = blockIdx.x * 256 + threadIdx.x;  // over NTOK*D/4
  const float4 v = ((const float4*)in)[i];
  short4 o;
  o.x = f2b(v.x); o.y = f2b(v.y); o.z = f2b(v.z); o.w = f2b(v.w);
  ((short4*)out)[i] = o;
}

// in [R][C] f32 -> out [C][R] bf16, batched over z. 64x64 tiles, float4 loads,
// LDS stored transposed (pad 69 -> <=2-way bank conflicts), short4 stores.
__global__ __launch_bounds__(256) void transpose_cvt(const float* __restrict__ in,
                                                     short* __restrict__ out,
                                                     int R, int C) {
  __shared__ float tile[64][69];  // tile[col][row]
  const int t = threadIdx.x;
  const int c0 = blockIdx.x * 64;
  const int r0 = blockIdx.y * 64;
  const size_t bo = (size_t)blockIdx.z * R * C;
  const int lr = t >> 4;          // 0..15
  const int lc4 = (t & 15) * 4;   // 0..60
#pragma unroll
  for (int i = 0; i < 4; i++) {
    const float4 v = *(const float4*)&in[bo + (size_t)(r0 + lr + i * 16) * C + c0 + lc4];
    tile[lc4 + 0][lr + i * 16] = v.x;
    tile[lc4 + 1][lr + i * 16] = v.y;
    tile[lc4 + 2][lr + i * 16] = v.z;
    tile[lc4 + 3][lr + i * 16] = v.w;
  }
  __syncthreads();
#pragma unroll
  for (int i = 0; i < 4; i++) {
    const int oc = (t >> 4) + i * 16;  // local out row (= in col)
    const int or4 = (t & 15) * 4;      // local out col (= in row)
    short4 o;
    o.x = f2b(tile[oc][or4 + 0]);
    o.y = f2b(tile[oc][or4 + 1]);
    o.z = f2b(tile[oc][or4 + 2]);
    o.w = f2b(tile[oc][or4 + 3]);
    *(short4*)&out[bo + (size_t)(c0 + oc) * R + r0 + or4] = o;
  }
}

// ---------------- router (wave per token, float4) ----------------
__global__ __launch_bounds__(256) void router_kernel(
    const float* __restrict__ x, const float* __restrict__ temb,
    const float* __restrict__ rw, const float* __restrict__ rbias,
    int* __restrict__ topk, float* __restrict__ gates) {
  const int t = (blockIdx.x * 256 + threadIdx.x) >> 6;
  const int lane = threadIdx.x & 63;
  const float* xr = x + (size_t)t * D_MODEL;
  const float* tr = temb + (size_t)(t >> 10) * D_MODEL;  // T=1024
  float acc[NEXP] = {};
#pragma unroll
  for (int i = 0; i < 4; i++) {
    const int j = i * 256 + lane * 4;
    const float4 xv = *(const float4*)&xr[j];
    const float4 tv = *(const float4*)&tr[j];
    const float* wx = rw + (size_t)j * NEXP;
    const float* wt = rw + (size_t)(D_MODEL + j) * NEXP;
    const float xa[4] = {xv.x, xv.y, xv.z, xv.w};
    const float ta[4] = {tv.x, tv.y, tv.z, tv.w};
#pragma unroll
    for (int u = 0; u < 4; u++)
#pragma unroll
      for (int e = 0; e < NEXP; e++)
        acc[e] += xa[u] * wx[u * NEXP + e] + ta[u] * wt[u * NEXP + e];
  }
#pragma unroll
  for (int off = 32; off; off >>= 1)
#pragma unroll
    for (int e = 0; e < NEXP; e++) acc[e] += __shfl_xor(acc[e], off);
  if (lane == 0) {
    float s[NEXP], sel[NEXP];
#pragma unroll
    for (int e = 0; e < NEXP; e++) {
      s[e] = 1.f / (1.f + expf(-acc[e]));
      sel[e] = s[e] + rbias[e];
    }
    int i0 = 0;
#pragma unroll
    for (int e = 1; e < NEXP; e++) if (sel[e] > sel[i0]) i0 = e;
    int i1 = (i0 == 0) ? 1 : 0;
#pragma unroll
    for (int e = 0; e < NEXP; e++) if (e != i0 && sel[e] > sel[i1]) i1 = e;
    float s0 = s[i0], s1 = s[i1], den = s0 + s1;
    float g0, g1;
    if (den > 1e-9f) { g0 = s0 / (den + 1e-9f); g1 = s1 / (den + 1e-9f); }
    else { g0 = 0.5f; g1 = 0.5f; }
    topk[t * 2] = i0; topk[t * 2 + 1] = i1;
    gates[t * 2] = g0; gates[t * 2 + 1] = g1;
  }
}

// ---------------- grouping: hist + scan + fill in one block ----------------
__global__ __launch_bounds__(1024) void group_kernel(const int* __restrict__ topk,
                                                     int* __restrict__ perm,
                                                     int* __restrict__ offs) {
  __shared__ int cnt[NEXP], cur[NEXP];
  const int t = threadIdx.x;
  if (t < NEXP) cnt[t] = 0;
  __syncthreads();
  int myе_dummy;
  (void)myе_dummy;
  int mye[8];
#pragma unroll
  for (int i = 0; i < 8; i++) {
    mye[i] = topk[i * 1024 + t];
    atomicAdd(&cnt[mye[i]], 1);
  }
  __syncthreads();
  if (t == 0) {
    int a = 0;
    for (int e = 0; e < NEXP; e++) { offs[e] = a; cur[e] = a; a += cnt[e]; }
    offs[NEXP] = a;
  }
  __syncthreads();
#pragma unroll
  for (int i = 0; i < 8; i++) {
    int pos = atomicAdd(&cur[mye[i]], 1);
    perm[pos] = i * 1024 + t;
  }
}

// ---------------- G1: u = silu(x@w1) * (x@w3), fused, bf16 out ----------------
// B = w13T [4096][1024]: rows 0..2047 = w1T, rows 2048..4095 = w3T
__global__ __launch_bounds__(256, 2) void gemm_g1(
    const short* __restrict__ A, const short* __restrict__ B, short* __restrict__ U) {
  __shared__ __align__(16) short As[4096];  // [128][32]
  __shared__ __align__(16) short Bs[4096];
  const int t = threadIdx.x;
  const int tile_n = blockIdx.x * 128;  // over HS
  const int m0 = blockIdx.y * 128;
  const int r = t >> 2;
  const int c8 = (t & 3) * 8;
  const short* Ap0 = A + (size_t)(m0 + r) * D_MODEL + c8;
  const short* Ap1 = A + (size_t)(m0 + 64 + r) * D_MODEL + c8;
  const short* Bp0 = B + (size_t)(tile_n + r) * D_MODEL + c8;
  const short* Bp1 = B + (size_t)(tile_n + 64 + r) * D_MODEL + c8;
  const size_t w3off = (size_t)HS * D_MODEL;

  const int lane = t & 63, wv = t >> 6;
  const int wm = (wv >> 1) * 64, wn = (wv & 1) * 64;
  const int lr = lane & 15, lk = (lane >> 4) * 8;

  f32x4 acca[4][4] = {};
  f32x4 accb[4][4] = {};

  for (int k0 = 0; k0 < D_MODEL; k0 += 32) {
    gl_lds16(Ap0 + k0, &As[t * 8]);
    gl_lds16(Ap1 + k0, &As[2048 + t * 8]);
    gl_lds16(Bp0 + k0, &Bs[t * 8]);
    gl_lds16(Bp1 + k0, &Bs[2048 + t * 8]);
    __syncthreads();
    bf16x8 af[4], bfr[4];
#pragma unroll
    for (int m = 0; m < 4; m++) af[m] = *(const bf16x8*)&As[(wm + m * 16 + lr) * 32 + lk];
#pragma unroll
    for (int n = 0; n < 4; n++) bfr[n] = *(const bf16x8*)&Bs[(wn + n * 16 + lr) * 32 + lk];
#pragma unroll
    for (int m = 0; m < 4; m++)
#pragma unroll
      for (int n = 0; n < 4; n++)
        acca[m][n] = __builtin_amdgcn_mfma_f32_16x16x32_bf16(af[m], bfr[n], acca[m][n], 0, 0, 0);
    __syncthreads();
  }
  for (int k0 = 0; k0 < D_MODEL; k0 += 32) {
    gl_lds16(Ap0 + k0, &As[t * 8]);
    gl_lds16(Ap1 + k0, &As[2048 + t * 8]);
    gl_lds16(Bp0 + w3off + k0, &Bs[t * 8]);
    gl_lds16(Bp1 + w3off + k0, &Bs[2048 + t * 8]);
    __syncthreads();
    bf16x8 af[4], bfr[4];
#pragma unroll
    for (int m = 0; m < 4; m++) af[m] = *(const bf16x8*)&As[(wm + m * 16 + lr) * 32 + lk];
#pragma unroll
    for (int n = 0; n < 4; n++) bfr[n] = *(const bf16x8*)&Bs[(wn + n * 16 + lr) * 32 + lk];
#pragma unroll
    for (int m = 0; m < 4; m++)
#pragma unroll
      for (int n = 0; n < 4; n++)
        accb[m][n] = __builtin_amdgcn_mfma_f32_16x16x32_bf16(af[m], bfr[n], accb[m][n], 0, 0, 0);
    __syncthreads();
  }

  const int rq = (lane >> 4) * 4;
#pragma unroll
  for (int m = 0; m < 4; m++) {
#pragma unroll
    for (int j = 0; j < 4; j++) {
      const int row = m0 + wm + m * 16 + rq + j;
      short* Up = U + (size_t)row * HS + tile_n + wn + lr;
#pragma unroll
      for (int n = 0; n < 4; n++) {
        const float a = acca[m][n][j];
        const float b = accb[m][n][j];
        Up[n * 16] = f2b(a / (1.f + expf(-a)) * b);
      }
    }
  }
}

// ---------------- grouped GEMMs ----------------
// MODE 1: gather A rows via perm>>1, exact-GELU epilogue -> bf16 rows at slot order (gi)
// MODE 2: A dense in perm order, gate-scale + scatter bf16 rows via perm
template <int MODE>
__global__ __launch_bounds__(256, 2) void gemm_grouped(
    const short* __restrict__ A, const short* __restrict__ B, short* __restrict__ C,
    const int* __restrict__ perm, const int* __restrict__ offs,
    const float* __restrict__ gates) {
  __shared__ __align__(16) short As[4096];
  __shared__ __align__(16) short Bs[4096];
  const int t = threadIdx.x;
  const int tile_n = blockIdx.x * 128;
  const int m0 = blockIdx.y * 128;
  const int e = blockIdx.z;
  const int rbeg = offs[e], rend = offs[e + 1];
  if (m0 >= rend - rbeg) return;
  const int K = (MODE == 1) ? D_MODEL : HE;
  const short* Bp = B + (size_t)e * (size_t)HE * D_MODEL;

  const int r = t >> 2;
  const int c8 = (t & 3) * 8;
  size_t arow0, arow1;
  {
    int gi0 = min(rbeg + m0 + r, rend - 1);
    int gi1 = min(rbeg + m0 + 64 + r, rend - 1);
    if (MODE == 1) {
      arow0 = (size_t)(perm[gi0] >> 1) * K;
      arow1 = (size_t)(perm[gi1] >> 1) * K;
    } else {
      arow0 = (size_t)gi0 * K;
      arow1 = (size_t)gi1 * K;
    }
  }
  const short* Ap0 = A + arow0 + c8;
  const short* Ap1 = A + arow1 + c8;
  const short* Bp0 = Bp + (size_t)(tile_n + r) * K + c8;
  const short* Bp1 = Bp + (size_t)(tile_n + 64 + r) * K + c8;

  const int lane = t & 63, wv = t >> 6;
  const int wm = (wv >> 1) * 64, wn = (wv & 1) * 64;
  const int lr = lane & 15, lk = (lane >> 4) * 8;

  f32x4 acc[4][4] = {};
  for (int k0 = 0; k0 < K; k0 += 32) {
    gl_lds16(Ap0 + k0, &As[t * 8]);
    gl_lds16(Ap1 + k0, &As[2048 + t * 8]);
    gl_lds16(Bp0 + k0, &Bs[t * 8]);
    gl_lds16(Bp1 + k0, &Bs[2048 + t * 8]);
    __syncthreads();
    bf16x8 af[4], bfr[4];
#pragma unroll
    for (int m = 0; m < 4; m++) af[m] = *(const bf16x8*)&As[(wm + m * 16 + lr) * 32 + lk];
#pragma unroll
    for (int n = 0; n < 4; n++) bfr[n] = *(const bf16x8*)&Bs[(wn + n * 16 + lr) * 32 + lk];
#pragma unroll
    for (int m = 0; m < 4; m++)
#pragma unroll
      for (int n = 0; n < 4; n++)
        acc[m][n] = __builtin_amdgcn_mfma_f32_16x16x32_bf16(af[m], bfr[n], acc[m][n], 0, 0, 0);
    __syncthreads();
  }

  const int rq = (lane >> 4) * 4;
#pragma unroll
  for (int m = 0; m < 4; m++) {
#pragma unroll
    for (int j = 0; j < 4; j++) {
      const int gi = rbeg + m0 + wm + m * 16 + rq + j;
      if (gi < rend) {
        if (MODE == 1) {
          short* Cp = C + (size_t)gi * HE + tile_n + wn + lr;
#pragma unroll
          for (int n = 0; n < 4; n++) {
            float v = acc[m][n][j];
            Cp[n * 16] = f2b(0.5f * v * (1.0f + erff(v * 0.70710678118654752f)));
          }
        } else {
          const int slot = perm[gi];
          const float g = gates[slot];
          short* Cp = C + (size_t)slot * D_MODEL + tile_n + wn + lr;
#pragma unroll
          for (int n = 0; n < 4; n++) Cp[n * 16] = f2b(g * acc[m][n][j]);
        }
      }
    }
  }
}

// ---------------- G2: shared = u @ w2, fused final combine ----------------
__global__ __launch_bounds__(256, 2) void gemm_g2(
    const short* __restrict__ A, const short* __restrict__ B,
    const short* __restrict__ yb, float* __restrict__ out) {
  __shared__ __align__(16) short As[4096];
  __shared__ __align__(16) short Bs[4096];
  const int t = threadIdx.x;
  const int tile_n = blockIdx.x * 128;  // over D_MODEL
  const int m0 = blockIdx.y * 128;
  const int r = t >> 2;
  const int c8 = (t & 3) * 8;
  const short* Ap0 = A + (size_t)(m0 + r) * HS + c8;
  const short* Ap1 = A + (size_t)(m0 + 64 + r) * HS + c8;
  const short* Bp0 = B + (size_t)(tile_n + r) * HS + c8;
  const short* Bp1 = B + (size_t)(tile_n + 64 + r) * HS + c8;

  const int lane = t & 63, wv = t >> 6;
  const int wm = (wv >> 1) * 64, wn = (wv & 1) * 64;
  const int lr = lane & 15, lk = (lane >> 4) * 8;

  f32x4 acc[4][4] = {};
  for (int k0 = 0; k0 < HS; k0 += 32) {
    gl_lds16(Ap0 + k0, &As[t * 8]);
    gl_lds16(Ap1 + k0, &As[2048 + t * 8]);
    gl_lds16(Bp0 + k0, &Bs[t * 8]);
    gl_lds16(Bp1 + k0, &Bs[2048 + t * 8]);
    __syncthreads();
    bf16x8 af[4], bfr[4];
#pragma unroll
    for (int m = 0; m < 4; m++) af[m] = *(const bf16x8*)&As[(wm + m * 16 + lr) * 32 + lk];
#pragma unroll
    for (int n = 0; n < 4; n++) bfr[n] = *(const bf16x8*)&Bs[(wn + n * 16 + lr) * 32 + lk];
#pragma unroll
    for (int m = 0; m < 4; m++)
#pragma unroll
      for (int n = 0; n < 4; n++)
        acc[m][n] = __builtin_amdgcn_mfma_f32_16x16x32_bf16(af[m], bfr[n], acc[m][n], 0, 0, 0);
    __syncthreads();
  }

  const int rq = (lane >> 4) * 4;
  const float inv3 = 1.0f / 3.0f;
#pragma unroll
  for (int m = 0; m < 4; m++) {
#pragma unroll
    for (int j = 0; j < 4; j++) {
      const int tok = m0 + wm + m * 16 + rq + j;
      const int colb = tile_n + wn + lr;
      const short* y0p = yb + (size_t)(tok * 2) * D_MODEL + colb;
      const short* y1p = yb + (size_t)(tok * 2 + 1) * D_MODEL + colb;
      float* Op = out + (size_t)tok * D_MODEL + colb;
#pragma unroll
      for (int n = 0; n < 4; n++) {
        Op[n * 16] = (acc[m][n][j] + b2f(y0p[n * 16]) + b2f(y1p[n * 16])) * inv3;
      }
    }
  }
}

// ---------------- launch ----------------
extern "C" void kernel_launch(void* const* d_in, const int* in_sizes, int n_in,
                              void* d_out, int out_size, void* d_ws, size_t ws_size,
                              hipStream_t stream) {
  const float* x = (const float*)d_in[0];
  const float* temb = (const float*)d_in[1];
  const float* rw = (const float*)d_in[2];
  const float* rbias = (const float*)d_in[3];
  const float* w1 = (const float*)d_in[4];
  const float* w3 = (const float*)d_in[5];
  const float* w2 = (const float*)d_in[6];
  const float* W1e = (const float*)d_in[7];
  const float* W2e = (const float*)d_in[8];
  float* out = (float*)d_out;

  const size_t MB = 1ull << 20;
  char* w = (char*)d_ws;
  short* xb    = (short*)(w + 0 * MB);    // 8 MB  [4096][1024]
  short* w13T  = (short*)(w + 8 * MB);    // 8 MB  [4096][1024] (w1T | w3T)
  short* w2T   = (short*)(w + 16 * MB);   // 4 MB  [1024][2048]
  short* W1eT  = (short*)(w + 20 * MB);   // 16 MB [8][1024][1024]
  short* W2eT  = (short*)(w + 36 * MB);   // 16 MB [8][1024][1024]
  short* ubuf  = (short*)(w + 52 * MB);   // 16 MB [4096][2048]
  short* hexpb = (short*)(w + 68 * MB);   // 16 MB [8192][1024]
  short* yb    = (short*)(w + 84 * MB);   // 16 MB [8192][1024] gated bf16
  float* gates = (float*)(w + 100 * MB);  // 32 KB
  int* topk    = (int*)(w + 100 * MB + 32 * 1024);
  int* perm    = (int*)(w + 100 * MB + 64 * 1024);
  int* offs    = (int*)(w + 100 * MB + 96 * 1024);

  // converts / transposes
  cvt_x_kernel<<<NTOK * D_MODEL / 4 / 256, 256, 0, stream>>>(x, xb);
  transpose_cvt<<<dim3(HS / 64, D_MODEL / 64, 1), 256, 0, stream>>>(w1, w13T, D_MODEL, HS);
  transpose_cvt<<<dim3(HS / 64, D_MODEL / 64, 1), 256, 0, stream>>>(w3, w13T + (size_t)HS * D_MODEL, D_MODEL, HS);
  transpose_cvt<<<dim3(D_MODEL / 64, HS / 64, 1), 256, 0, stream>>>(w2, w2T, HS, D_MODEL);
  transpose_cvt<<<dim3(HE / 64, D_MODEL / 64, NEXP), 256, 0, stream>>>(W1e, W1eT, D_MODEL, HE);
  transpose_cvt<<<dim3(D_MODEL / 64, HE / 64, NEXP), 256, 0, stream>>>(W2e, W2eT, HE, D_MODEL);

  // router + grouping
  router_kernel<<<NTOK / 4, 256, 0, stream>>>(x, temb, rw, rbias, topk, gates);
  group_kernel<<<1, 1024, 0, stream>>>(topk, perm, offs);

  // shared expert up-proj fused with silu*mul
  gemm_g1<<<dim3(HS / 128, NTOK / 128, 1), 256, 0, stream>>>(xb, w13T, ubuf);

  // routed experts (must finish before gemm_g2's combine epilogue)
  gemm_grouped<1><<<dim3(HE / 128, NSLOT / 128, NEXP), 256, 0, stream>>>(
      xb, W1eT, hexpb, perm, offs, gates);
  gemm_grouped<2><<<dim3(D_MODEL / 128, NSLOT / 128, NEXP), 256, 0, stream>>>(
      hexpb, W2eT, yb, perm, offs, gates);

  // shared down-proj + final combine
  gemm_g2<<<dim3(D_MODEL / 128, NTOK / 128, 1), 256, 0, stream>>>(ubuf, w2T, yb, out);
}